// Round 9
// baseline (143.040 us; speedup 1.0000x reference)
//
#include <hip/hip_runtime.h>

#define LN_EPS 1e-5f

constexpr int Bn = 4, Nn = 256, Dn = 256, Hn = 256;

// ws layout (floats):
//   aA    @ 0        (1024*256)
//   bB    @ 262144   (1024*256)
//   rC    @ 524288   (1024)      -- atomic accumulators r[b,h], zeroed in gemm
//   Cpart @ 525312   (512)
//   rel   @ 525824   (1024)
//   rC2   @ 527360 / Cpart2 @ 528384   -- dummy outputs for timing copy 2
//   rC3   @ 528896 / Cpart3 @ 529920   -- dummy outputs for timing copy 3
// MEASUREMENT ROUND: pair_kernel launched 3x (copies 2,3 into dummy buffers,
// poisoned init, never read) => T_pair = (dur - 103.2)/2 approx.

// ---------------------------------------------------------------------------
// Kernel 1: identical to round 8.
// ---------------------------------------------------------------------------
__global__ __launch_bounds__(512) void gemm_ab_kernel(
    const float* __restrict__ x, const float* __restrict__ Wg,
    const float* __restrict__ bg, float* __restrict__ aA,
    float* __restrict__ bB, float* __restrict__ rC)
{
    int mt = blockIdx.x;     // 0..255
    int half = blockIdx.y;   // 0 -> a, 1 -> b
    int m0 = mt * 4;
    int t = threadIdx.x;

    if (mt == 0 && half == 0) {
        for (int k = t; k < 1024; k += 512) rC[k] = 0.0f;
    }

    __shared__ float xs[4][256];
    __shared__ float accP[8][4][256];

    if (t < 256)
        reinterpret_cast<float4*>(&xs[0][0])[t] =
            reinterpret_cast<const float4*>(x + m0 * Dn)[t];
    __syncthreads();

    int h4 = t & 63;
    int dc = t >> 6;         // wave-uniform
    const float* Wp = Wg + (half ? Dn * Hn : 0) + h4 * 4;

    float4 acc[4];
#pragma unroll
    for (int m = 0; m < 4; ++m) acc[m] = make_float4(0.f, 0.f, 0.f, 0.f);

#pragma unroll 4
    for (int dd = 0; dd < 32; ++dd) {
        int d = dc * 32 + dd;
        float4 w = *reinterpret_cast<const float4*>(Wp + d * Hn);
#pragma unroll
        for (int m = 0; m < 4; ++m) {
            float xv = xs[m][d];
            acc[m].x = fmaf(xv, w.x, acc[m].x);
            acc[m].y = fmaf(xv, w.y, acc[m].y);
            acc[m].z = fmaf(xv, w.z, acc[m].z);
            acc[m].w = fmaf(xv, w.w, acc[m].w);
        }
    }
#pragma unroll
    for (int m = 0; m < 4; ++m)
        *reinterpret_cast<float4*>(&accP[dc][m][h4 * 4]) = acc[m];
    __syncthreads();

    int h = t & 255;
    int mh = t >> 8;
    float binit = half ? 0.0f : bg[h];
    float* outp = half ? bB : aA;
#pragma unroll
    for (int mi = 0; mi < 2; ++mi) {
        int m = mh * 2 + mi;
        float v = binit;
#pragma unroll
        for (int c = 0; c < 8; ++c) v += accP[c][m][h];
        outp[(m0 + m) * Hn + h] = v;
    }
}

// ---------------------------------------------------------------------------
// Kernel 2: identical to round 8 (double-buffered, 8 barriers, (512,2)).
// ---------------------------------------------------------------------------
__global__ __launch_bounds__(512, 2) void pair_kernel(
    const float* __restrict__ aA, const float* __restrict__ bB,
    float* __restrict__ rC, float* __restrict__ Cpart)
{
    const int b  = blockIdx.x >> 7;
    const int i0 = (blockIdx.x & 127) * 2;
    const int t  = threadIdx.x;

    __shared__ float Bs[2][32][260];
    __shared__ float invL[2][2][32];
    __shared__ float wred[8];

    const int jg = t >> 4;
    const int p  = t & 15;
    const int h4 = t & 63;
    const int c  = t >> 6;    // wave-uniform

    const float* aArow0 = aA + (b * Nn + i0) * Hn;
    const float* aArow1 = aArow0 + Hn;

    float4 As0[4], As1[4];
#pragma unroll
    for (int r = 0; r < 4; ++r) {
        As0[r] = *reinterpret_cast<const float4*>(aArow0 + 4 * (p + 16 * r));
        As1[r] = *reinterpret_cast<const float4*>(aArow1 + 4 * (p + 16 * r));
    }
    const float4 a0 = *reinterpret_cast<const float4*>(aArow0 + h4 * 4);
    const float4 a1 = *reinterpret_cast<const float4*>(aArow1 + h4 * 4);

    const float* browbase = bB + b * Nn * Hn;

    float4 acc0 = make_float4(0.f, 0.f, 0.f, 0.f);
    float4 acc1 = make_float4(0.f, 0.f, 0.f, 0.f);
    float Csum = 0.f;

    float4 bv[4], bvn[4];
    {
        const float* rp = browbase + jg * Hn;
#pragma unroll
        for (int r = 0; r < 4; ++r)
            bv[r] = *reinterpret_cast<const float4*>(rp + 4 * (p + 16 * r));
    }

    for (int jt = 0; jt < 8; ++jt) {
        const int kb = jt & 1;
        float s0 = 0.f, q0 = 0.f, s1 = 0.f, q1 = 0.f;
#pragma unroll
        for (int r = 0; r < 4; ++r) {
            float v;
            v = fmaxf(As0[r].x + bv[r].x, 0.f); s0 += v; q0 = fmaf(v, v, q0);
            v = fmaxf(As0[r].y + bv[r].y, 0.f); s0 += v; q0 = fmaf(v, v, q0);
            v = fmaxf(As0[r].z + bv[r].z, 0.f); s0 += v; q0 = fmaf(v, v, q0);
            v = fmaxf(As0[r].w + bv[r].w, 0.f); s0 += v; q0 = fmaf(v, v, q0);
            v = fmaxf(As1[r].x + bv[r].x, 0.f); s1 += v; q1 = fmaf(v, v, q1);
            v = fmaxf(As1[r].y + bv[r].y, 0.f); s1 += v; q1 = fmaf(v, v, q1);
            v = fmaxf(As1[r].z + bv[r].z, 0.f); s1 += v; q1 = fmaf(v, v, q1);
            v = fmaxf(As1[r].w + bv[r].w, 0.f); s1 += v; q1 = fmaf(v, v, q1);
        }
#pragma unroll
        for (int r = 0; r < 4; ++r)
            *reinterpret_cast<float4*>(&Bs[kb][jg][4 * (p + 16 * r)]) = bv[r];
        if (jt < 7) {
            const float* rp = browbase + ((jt + 1) * 32 + jg) * Hn;
#pragma unroll
            for (int r = 0; r < 4; ++r)
                bvn[r] = *reinterpret_cast<const float4*>(rp + 4 * (p + 16 * r));
        }
#pragma unroll
        for (int off = 8; off >= 1; off >>= 1) {
            s0 += __shfl_xor(s0, off, 16);
            q0 += __shfl_xor(q0, off, 16);
            s1 += __shfl_xor(s1, off, 16);
            q1 += __shfl_xor(q1, off, 16);
        }
        if (p == 0) {
            float m0 = s0 * (1.f / 256.f), m1 = s1 * (1.f / 256.f);
            float inv0 = rsqrtf(q0 * (1.f / 256.f) - m0 * m0 + LN_EPS);
            float inv1 = rsqrtf(q1 * (1.f / 256.f) - m1 * m1 + LN_EPS);
            invL[kb][0][jg] = inv0;
            invL[kb][1][jg] = inv1;
            Csum -= m0 * inv0 + m1 * inv1;
        }
        __syncthreads();
        {
            const float4 w0v = *reinterpret_cast<const float4*>(&invL[kb][0][c * 4]);
            const float4 w1v = *reinterpret_cast<const float4*>(&invL[kb][1][c * 4]);
            const float w0a[4] = {w0v.x, w0v.y, w0v.z, w0v.w};
            const float w1a[4] = {w1v.x, w1v.y, w1v.z, w1v.w};
#pragma unroll
            for (int jj = 0; jj < 4; ++jj) {
                int j = c * 4 + jj;
                float w0 = w0a[jj];
                float w1 = w1a[jj];
                float4 b4 = *reinterpret_cast<const float4*>(&Bs[kb][j][h4 * 4]);
                acc0.x = fmaf(w0, fmaxf(a0.x + b4.x, 0.f), acc0.x);
                acc0.y = fmaf(w0, fmaxf(a0.y + b4.y, 0.f), acc0.y);
                acc0.z = fmaf(w0, fmaxf(a0.z + b4.z, 0.f), acc0.z);
                acc0.w = fmaf(w0, fmaxf(a0.w + b4.w, 0.f), acc0.w);
                acc1.x = fmaf(w1, fmaxf(a1.x + b4.x, 0.f), acc1.x);
                acc1.y = fmaf(w1, fmaxf(a1.y + b4.y, 0.f), acc1.y);
                acc1.z = fmaf(w1, fmaxf(a1.z + b4.z, 0.f), acc1.z);
                acc1.w = fmaf(w1, fmaxf(a1.w + b4.w, 0.f), acc1.w);
            }
        }
        if (jt < 7) {
#pragma unroll
            for (int r = 0; r < 4; ++r) bv[r] = bvn[r];
        }
    }

    float* red = &Bs[0][0][0];
    *reinterpret_cast<float4*>(red + c * 256 + h4 * 4) = acc0;
    *reinterpret_cast<float4*>(red + (8 + c) * 256 + h4 * 4) = acc1;

    float cs = Csum;
#pragma unroll
    for (int off = 32; off >= 1; off >>= 1) cs += __shfl_xor(cs, off, 64);
    if ((t & 63) == 0) wred[t >> 6] = cs;
    __syncthreads();

    if (t < 256) {
        float v = 0.f;
#pragma unroll
        for (int cc = 0; cc < 8; ++cc)
            v += red[cc * 256 + t] + red[(8 + cc) * 256 + t];
        atomicAdd(&rC[b * Hn + t], v);
    }
    if (t == 0) {
        float cb = 0.f;
#pragma unroll
        for (int w = 0; w < 8; ++w) cb += wred[w];
        Cpart[blockIdx.x] = cb;
    }
}

// ---------------------------------------------------------------------------
// Kernel 3: identical to round 8.
// ---------------------------------------------------------------------------
__global__ __launch_bounds__(512) void finish_kernel(
    const float* __restrict__ rC, const float* __restrict__ Cpart,
    const float* __restrict__ gg, const float* __restrict__ gb,
    const float* __restrict__ Wf, const float* __restrict__ bfv,
    const float* __restrict__ fg, const float* __restrict__ fb,
    float* __restrict__ rel)
{
    const int b = blockIdx.x;
    const int t = threadIdx.x;
    __shared__ float rs[256];
    __shared__ float ysum[8][260];
    __shared__ float cred[2];
    __shared__ float pS[4], pQ[4];

    float cv = (t < 128) ? Cpart[b * 128 + t] : 0.f;
#pragma unroll
    for (int off = 32; off >= 1; off >>= 1) cv += __shfl_xor(cv, off, 64);
    if (t == 0 || t == 64) cred[t >> 6] = cv;
    __syncthreads();

    if (t < 256) {
        float Cb = cred[0] + cred[1];
        rs[t] = gg[t] * (rC[b * Hn + t] + Cb) + 65536.0f * gb[t];
    }
    __syncthreads();

    const int h4 = t & 63;
    const int kc = t >> 6;   // 0..7, 32 k each
    float4 acc = make_float4(0.f, 0.f, 0.f, 0.f);
    const float* Wp = Wf + h4 * 4;
#pragma unroll 8
    for (int kk = 0; kk < 32; ++kk) {
        int k = kc * 32 + kk;
        float4 w = *reinterpret_cast<const float4*>(Wp + k * Hn);
        float rv = rs[k];
        acc.x = fmaf(rv, w.x, acc.x);
        acc.y = fmaf(rv, w.y, acc.y);
        acc.z = fmaf(rv, w.z, acc.z);
        acc.w = fmaf(rv, w.w, acc.w);
    }
    *reinterpret_cast<float4*>(&ysum[kc][h4 * 4]) = acc;
    __syncthreads();

    float v = 0.f;
    if (t < 256) {
        v = bfv[t];
#pragma unroll
        for (int c = 0; c < 8; ++c) v += ysum[c][t];
        v = fmaxf(v, 0.f);
    }
    float sv = (t < 256) ? v : 0.f;
    float qv = (t < 256) ? v * v : 0.f;
#pragma unroll
    for (int off = 32; off >= 1; off >>= 1) {
        sv += __shfl_xor(sv, off, 64);
        qv += __shfl_xor(qv, off, 64);
    }
    if (t < 256 && (t & 63) == 0) { pS[t >> 6] = sv; pQ[t >> 6] = qv; }
    __syncthreads();

    if (t < 256) {
        float S = pS[0] + pS[1] + pS[2] + pS[3];
        float Q = pQ[0] + pQ[1] + pQ[2] + pQ[3];
        float m = S * (1.f / 256.f);
        float inv = rsqrtf(Q * (1.f / 256.f) - m * m + LN_EPS);
        rel[b * Hn + t] = (v - m) * inv * fg[t] + fb[t];
    }
}

// ---------------------------------------------------------------------------
// Kernel 4: identical to round 8.
// ---------------------------------------------------------------------------
__global__ __launch_bounds__(256) void add_kernel(
    const float* __restrict__ rel, const float* __restrict__ x,
    float* __restrict__ out)
{
    int idx = blockIdx.x * blockDim.x + threadIdx.x;   // float4 units
    int b = idx >> 14;
    int d4 = idx & 63;
    float4 r4 = reinterpret_cast<const float4*>(rel)[b * 64 + d4];
    float4 x4 = reinterpret_cast<const float4*>(x)[idx];
    float4 o;
    o.x = r4.x + x4.x;
    o.y = r4.y + x4.y;
    o.z = r4.z + x4.z;
    o.w = r4.w + x4.w;
    reinterpret_cast<float4*>(out)[idx] = o;
}

// ---------------------------------------------------------------------------
extern "C" void kernel_launch(void* const* d_in, const int* in_sizes, int n_in,
                              void* d_out, int out_size, void* d_ws, size_t ws_size,
                              hipStream_t stream)
{
    const float* x   = (const float*)d_in[0];
    const float* Wg  = (const float*)d_in[1];
    const float* bg  = (const float*)d_in[2];
    const float* gg  = (const float*)d_in[3];
    const float* gb  = (const float*)d_in[4];
    const float* Wf  = (const float*)d_in[5];
    const float* bfv = (const float*)d_in[6];
    const float* fg  = (const float*)d_in[7];
    const float* fb  = (const float*)d_in[8];
    float* out = (float*)d_out;

    float* ws     = (float*)d_ws;
    float* aA     = ws;                 // 1024*256
    float* bB     = ws + 262144;        // 1024*256
    float* rC     = ws + 524288;        // 1024
    float* Cpart  = ws + 525312;        // 512
    float* rel    = ws + 525824;        // 1024
    float* rC2    = ws + 527360;        // dummy (timing copy 2)
    float* Cpart2 = ws + 528384;
    float* rC3    = ws + 528896;        // dummy (timing copy 3)
    float* Cpart3 = ws + 529920;

    gemm_ab_kernel<<<dim3(256, 2), 512, 0, stream>>>(x, Wg, bg, aA, bB, rC);
    // real pair + 2 timing duplicates into dummy accumulators
    pair_kernel<<<512, 512, 0, stream>>>(aA, bB, rC, Cpart);
    pair_kernel<<<512, 512, 0, stream>>>(aA, bB, rC2, Cpart2);
    pair_kernel<<<512, 512, 0, stream>>>(aA, bB, rC3, Cpart3);
    finish_kernel<<<4, 512, 0, stream>>>(rC, Cpart, gg, gb, Wf, bfv, fg, fb, rel);
    add_kernel<<<256, 256, 0, stream>>>(rel, x, out);
}

// Round 10
// 117.044 us; speedup vs baseline: 1.2221x; 1.2221x over previous
//
#include <hip/hip_runtime.h>

#define LN_EPS 1e-5f

constexpr int Bn = 4, Nn = 256, Dn = 256, Hn = 256;

// ws layout (floats):
//   aA    @ 0        (1024*256)
//   bB    @ 262144   (1024*256)
//   rC    @ 524288   (1024)      -- atomic accumulators r[b,h], zeroed in gemm
//   Cpart @ 525312   (512)
//   rel   @ 525824   (1024)
// Timing ledger (measured): fill ~43 (in-window, untouchable), gemm ~29,
// pair ~19 (r9 3x-launch bracket), finish+add+gaps ~12.

// ---------------------------------------------------------------------------
// Kernel 1: identical to round 8.
// ---------------------------------------------------------------------------
__global__ __launch_bounds__(512) void gemm_ab_kernel(
    const float* __restrict__ x, const float* __restrict__ Wg,
    const float* __restrict__ bg, float* __restrict__ aA,
    float* __restrict__ bB, float* __restrict__ rC)
{
    int mt = blockIdx.x;     // 0..255
    int half = blockIdx.y;   // 0 -> a, 1 -> b
    int m0 = mt * 4;
    int t = threadIdx.x;

    if (mt == 0 && half == 0) {
        for (int k = t; k < 1024; k += 512) rC[k] = 0.0f;
    }

    __shared__ float xs[4][256];
    __shared__ float accP[8][4][256];

    if (t < 256)
        reinterpret_cast<float4*>(&xs[0][0])[t] =
            reinterpret_cast<const float4*>(x + m0 * Dn)[t];
    __syncthreads();

    int h4 = t & 63;
    int dc = t >> 6;         // wave-uniform
    const float* Wp = Wg + (half ? Dn * Hn : 0) + h4 * 4;

    float4 acc[4];
#pragma unroll
    for (int m = 0; m < 4; ++m) acc[m] = make_float4(0.f, 0.f, 0.f, 0.f);

#pragma unroll 4
    for (int dd = 0; dd < 32; ++dd) {
        int d = dc * 32 + dd;
        float4 w = *reinterpret_cast<const float4*>(Wp + d * Hn);
#pragma unroll
        for (int m = 0; m < 4; ++m) {
            float xv = xs[m][d];
            acc[m].x = fmaf(xv, w.x, acc[m].x);
            acc[m].y = fmaf(xv, w.y, acc[m].y);
            acc[m].z = fmaf(xv, w.z, acc[m].z);
            acc[m].w = fmaf(xv, w.w, acc[m].w);
        }
    }
#pragma unroll
    for (int m = 0; m < 4; ++m)
        *reinterpret_cast<float4*>(&accP[dc][m][h4 * 4]) = acc[m];
    __syncthreads();

    int h = t & 255;
    int mh = t >> 8;
    float binit = half ? 0.0f : bg[h];
    float* outp = half ? bB : aA;
#pragma unroll
    for (int mi = 0; mi < 2; ++mi) {
        int m = mh * 2 + mi;
        float v = binit;
#pragma unroll
        for (int c = 0; c < 8; ++c) v += accP[c][m][h];
        outp[(m0 + m) * Hn + h] = v;
    }
}

// ---------------------------------------------------------------------------
// Kernel 2: pair block, BARRIER-FREE single pass.
// Block = (b, 2 i-rows), 512 threads = (s = t>>4 in [0,32): j-slot,
//                                       p = t&15: h-group of 16).
// Per j-tile (32 rows): thread's j = jt*32+s. Load b[j][p*16..+15]
// (contiguous 64B/thread), v = relu(a+b) ONCE into registers, s/q stats,
// width-16 shuffle butterfly (stats for row j live in the 16 p-lanes),
// inv computed redundantly per lane, acc += inv*v from stashed v.
// NO LDS, NO barriers, no prefetch copies in the j-loop.
// Epilogue: cross-wave butterfly (xor 16,32) over the 32 acc floats,
// lanes (t&63)<16 write fred[w][p][33-padded], one barrier, 512-thread
// final reduce -> 1 atomicAdd per (i,h); Csum wave-reduced -> Cpart.
// ---------------------------------------------------------------------------
__global__ __launch_bounds__(512, 2) void pair_kernel(
    const float* __restrict__ aA, const float* __restrict__ bB,
    float* __restrict__ rC, float* __restrict__ Cpart)
{
    const int b  = blockIdx.x >> 7;
    const int i0 = (blockIdx.x & 127) * 2;
    const int t  = threadIdx.x;
    const int s  = t >> 4;    // j-slot 0..31
    const int p  = t & 15;    // h-group 0..15

    __shared__ float fred[8][16][33];   // [wave][p][i*16+hh], pad 33 (bank-safe)
    __shared__ float wred[8];

    // A fragments: a[i][h = p*16 + hh], hh = 0..15  (4 float4 per row)
    const float* aArow0 = aA + (b * Nn + i0) * Hn + p * 16;
    const float* aArow1 = aArow0 + Hn;
    float4 A0[4], A1[4];
#pragma unroll
    for (int r = 0; r < 4; ++r) {
        A0[r] = *reinterpret_cast<const float4*>(aArow0 + r * 4);
        A1[r] = *reinterpret_cast<const float4*>(aArow1 + r * 4);
    }

    const float* bbase = bB + b * Nn * Hn + p * 16;

    float4 acc0[4], acc1[4];
#pragma unroll
    for (int r = 0; r < 4; ++r) {
        acc0[r] = make_float4(0.f, 0.f, 0.f, 0.f);
        acc1[r] = make_float4(0.f, 0.f, 0.f, 0.f);
    }
    float Csum = 0.f;

    for (int jt = 0; jt < 8; ++jt) {
        const int j = jt * 32 + s;
        const float* rp = bbase + j * Hn;
        float4 bv[4];
#pragma unroll
        for (int r = 0; r < 4; ++r)
            bv[r] = *reinterpret_cast<const float4*>(rp + r * 4);

        // v = relu(a+b) once; accumulate s,q
        float4 v0[4], v1[4];
        float s0 = 0.f, q0 = 0.f, s1 = 0.f, q1 = 0.f;
#pragma unroll
        for (int r = 0; r < 4; ++r) {
            float4 w;
            w.x = fmaxf(A0[r].x + bv[r].x, 0.f);
            w.y = fmaxf(A0[r].y + bv[r].y, 0.f);
            w.z = fmaxf(A0[r].z + bv[r].z, 0.f);
            w.w = fmaxf(A0[r].w + bv[r].w, 0.f);
            v0[r] = w;
            s0 += w.x + w.y + w.z + w.w;
            q0 = fmaf(w.x, w.x, q0); q0 = fmaf(w.y, w.y, q0);
            q0 = fmaf(w.z, w.z, q0); q0 = fmaf(w.w, w.w, q0);
            float4 u;
            u.x = fmaxf(A1[r].x + bv[r].x, 0.f);
            u.y = fmaxf(A1[r].y + bv[r].y, 0.f);
            u.z = fmaxf(A1[r].z + bv[r].z, 0.f);
            u.w = fmaxf(A1[r].w + bv[r].w, 0.f);
            v1[r] = u;
            s1 += u.x + u.y + u.z + u.w;
            q1 = fmaf(u.x, u.x, q1); q1 = fmaf(u.y, u.y, q1);
            q1 = fmaf(u.z, u.z, q1); q1 = fmaf(u.w, u.w, q1);
        }
        // width-16 butterfly: stats for row j complete within the p-lanes
#pragma unroll
        for (int off = 1; off <= 8; off <<= 1) {
            s0 += __shfl_xor(s0, off, 16);
            q0 += __shfl_xor(q0, off, 16);
            s1 += __shfl_xor(s1, off, 16);
            q1 += __shfl_xor(q1, off, 16);
        }
        float m0 = s0 * (1.f / 256.f), m1 = s1 * (1.f / 256.f);
        float inv0 = rsqrtf(q0 * (1.f / 256.f) - m0 * m0 + LN_EPS);
        float inv1 = rsqrtf(q1 * (1.f / 256.f) - m1 * m1 + LN_EPS);
        if (p == 0) Csum -= m0 * inv0 + m1 * inv1;
        // weighted accumulate from stashed v
#pragma unroll
        for (int r = 0; r < 4; ++r) {
            acc0[r].x = fmaf(inv0, v0[r].x, acc0[r].x);
            acc0[r].y = fmaf(inv0, v0[r].y, acc0[r].y);
            acc0[r].z = fmaf(inv0, v0[r].z, acc0[r].z);
            acc0[r].w = fmaf(inv0, v0[r].w, acc0[r].w);
            acc1[r].x = fmaf(inv1, v1[r].x, acc1[r].x);
            acc1[r].y = fmaf(inv1, v1[r].y, acc1[r].y);
            acc1[r].z = fmaf(inv1, v1[r].z, acc1[r].z);
            acc1[r].w = fmaf(inv1, v1[r].w, acc1[r].w);
        }
    }

    // ---- cross-s reduce within wave: xor 16, 32 over all 32 acc floats ----
#pragma unroll
    for (int r = 0; r < 4; ++r) {
        acc0[r].x += __shfl_xor(acc0[r].x, 16, 64);
        acc0[r].y += __shfl_xor(acc0[r].y, 16, 64);
        acc0[r].z += __shfl_xor(acc0[r].z, 16, 64);
        acc0[r].w += __shfl_xor(acc0[r].w, 16, 64);
        acc1[r].x += __shfl_xor(acc1[r].x, 16, 64);
        acc1[r].y += __shfl_xor(acc1[r].y, 16, 64);
        acc1[r].z += __shfl_xor(acc1[r].z, 16, 64);
        acc1[r].w += __shfl_xor(acc1[r].w, 16, 64);
    }
#pragma unroll
    for (int r = 0; r < 4; ++r) {
        acc0[r].x += __shfl_xor(acc0[r].x, 32, 64);
        acc0[r].y += __shfl_xor(acc0[r].y, 32, 64);
        acc0[r].z += __shfl_xor(acc0[r].z, 32, 64);
        acc0[r].w += __shfl_xor(acc0[r].w, 32, 64);
        acc1[r].x += __shfl_xor(acc1[r].x, 32, 64);
        acc1[r].y += __shfl_xor(acc1[r].y, 32, 64);
        acc1[r].z += __shfl_xor(acc1[r].z, 32, 64);
        acc1[r].w += __shfl_xor(acc1[r].w, 32, 64);
    }
    const int w = t >> 6;
    if ((t & 63) < 16) {   // lane p of wave w holds the wave-partial
#pragma unroll
        for (int r = 0; r < 4; ++r) {
            fred[w][p][r * 4 + 0] = acc0[r].x;
            fred[w][p][r * 4 + 1] = acc0[r].y;
            fred[w][p][r * 4 + 2] = acc0[r].z;
            fred[w][p][r * 4 + 3] = acc0[r].w;
            fred[w][p][16 + r * 4 + 0] = acc1[r].x;
            fred[w][p][16 + r * 4 + 1] = acc1[r].y;
            fred[w][p][16 + r * 4 + 2] = acc1[r].z;
            fred[w][p][16 + r * 4 + 3] = acc1[r].w;
        }
    }
    // Csum: nonzero only on p==0 lanes; full-wave reduce
    float cs = Csum;
#pragma unroll
    for (int off = 32; off >= 1; off >>= 1) cs += __shfl_xor(cs, off, 64);
    if ((t & 63) == 0) wred[w] = cs;
    __syncthreads();

    {
        const int i  = t >> 8;          // 0..1
        const int h  = t & 255;
        const int pp = h >> 4, hh = h & 15;
        float v = 0.f;
#pragma unroll
        for (int ww = 0; ww < 8; ++ww) v += fred[ww][pp][i * 16 + hh];
        atomicAdd(&rC[(b * Nn + 0) * 0 + b * Hn + h + i * 0], 0.0f);  // no-op guard removed below
        // (two i-rows share the same r[b,h] accumulator: both add)
        atomicAdd(&rC[b * Hn + h], v);
    }
    if (t == 0) {
        float cb = 0.f;
#pragma unroll
        for (int ww = 0; ww < 8; ++ww) cb += wred[ww];
        Cpart[blockIdx.x] = cb;
    }
}

// ---------------------------------------------------------------------------
// Kernel 3: identical to round 8.
// ---------------------------------------------------------------------------
__global__ __launch_bounds__(512) void finish_kernel(
    const float* __restrict__ rC, const float* __restrict__ Cpart,
    const float* __restrict__ gg, const float* __restrict__ gb,
    const float* __restrict__ Wf, const float* __restrict__ bfv,
    const float* __restrict__ fg, const float* __restrict__ fb,
    float* __restrict__ rel)
{
    const int b = blockIdx.x;
    const int t = threadIdx.x;
    __shared__ float rs[256];
    __shared__ float ysum[8][260];
    __shared__ float cred[2];
    __shared__ float pS[4], pQ[4];

    float cv = (t < 128) ? Cpart[b * 128 + t] : 0.f;
#pragma unroll
    for (int off = 32; off >= 1; off >>= 1) cv += __shfl_xor(cv, off, 64);
    if (t == 0 || t == 64) cred[t >> 6] = cv;
    __syncthreads();

    if (t < 256) {
        float Cb = cred[0] + cred[1];
        rs[t] = gg[t] * (rC[b * Hn + t] + Cb) + 65536.0f * gb[t];
    }
    __syncthreads();

    const int h4 = t & 63;
    const int kc = t >> 6;   // 0..7, 32 k each
    float4 acc = make_float4(0.f, 0.f, 0.f, 0.f);
    const float* Wp = Wf + h4 * 4;
#pragma unroll 8
    for (int kk = 0; kk < 32; ++kk) {
        int k = kc * 32 + kk;
        float4 w = *reinterpret_cast<const float4*>(Wp + k * Hn);
        float rv = rs[k];
        acc.x = fmaf(rv, w.x, acc.x);
        acc.y = fmaf(rv, w.y, acc.y);
        acc.z = fmaf(rv, w.z, acc.z);
        acc.w = fmaf(rv, w.w, acc.w);
    }
    *reinterpret_cast<float4*>(&ysum[kc][h4 * 4]) = acc;
    __syncthreads();

    float v = 0.f;
    if (t < 256) {
        v = bfv[t];
#pragma unroll
        for (int c = 0; c < 8; ++c) v += ysum[c][t];
        v = fmaxf(v, 0.f);
    }
    float sv = (t < 256) ? v : 0.f;
    float qv = (t < 256) ? v * v : 0.f;
#pragma unroll
    for (int off = 32; off >= 1; off >>= 1) {
        sv += __shfl_xor(sv, off, 64);
        qv += __shfl_xor(qv, off, 64);
    }
    if (t < 256 && (t & 63) == 0) { pS[t >> 6] = sv; pQ[t >> 6] = qv; }
    __syncthreads();

    if (t < 256) {
        float S = pS[0] + pS[1] + pS[2] + pS[3];
        float Q = pQ[0] + pQ[1] + pQ[2] + pQ[3];
        float m = S * (1.f / 256.f);
        float inv = rsqrtf(Q * (1.f / 256.f) - m * m + LN_EPS);
        rel[b * Hn + t] = (v - m) * inv * fg[t] + fb[t];
    }
}

// ---------------------------------------------------------------------------
// Kernel 4: identical to round 8.
// ---------------------------------------------------------------------------
__global__ __launch_bounds__(256) void add_kernel(
    const float* __restrict__ rel, const float* __restrict__ x,
    float* __restrict__ out)
{
    int idx = blockIdx.x * blockDim.x + threadIdx.x;   // float4 units
    int b = idx >> 14;
    int d4 = idx & 63;
    float4 r4 = reinterpret_cast<const float4*>(rel)[b * 64 + d4];
    float4 x4 = reinterpret_cast<const float4*>(x)[idx];
    float4 o;
    o.x = r4.x + x4.x;
    o.y = r4.y + x4.y;
    o.z = r4.z + x4.z;
    o.w = r4.w + x4.w;
    reinterpret_cast<float4*>(out)[idx] = o;
}

// ---------------------------------------------------------------------------
extern "C" void kernel_launch(void* const* d_in, const int* in_sizes, int n_in,
                              void* d_out, int out_size, void* d_ws, size_t ws_size,
                              hipStream_t stream)
{
    const float* x   = (const float*)d_in[0];
    const float* Wg  = (const float*)d_in[1];
    const float* bg  = (const float*)d_in[2];
    const float* gg  = (const float*)d_in[3];
    const float* gb  = (const float*)d_in[4];
    const float* Wf  = (const float*)d_in[5];
    const float* bfv = (const float*)d_in[6];
    const float* fg  = (const float*)d_in[7];
    const float* fb  = (const float*)d_in[8];
    float* out = (float*)d_out;

    float* ws    = (float*)d_ws;
    float* aA    = ws;                 // 1024*256
    float* bB    = ws + 262144;        // 1024*256
    float* rC    = ws + 524288;        // 1024
    float* Cpart = ws + 525312;        // 512
    float* rel   = ws + 525824;        // 1024

    gemm_ab_kernel<<<dim3(256, 2), 512, 0, stream>>>(x, Wg, bg, aA, bB, rC);
    pair_kernel<<<512, 512, 0, stream>>>(aA, bB, rC, Cpart);
    finish_kernel<<<4, 512, 0, stream>>>(rC, Cpart, gg, gb, Wf, bfv, fg, fb, rel);
    add_kernel<<<256, 256, 0, stream>>>(rel, x, out);
}

// Round 11
// 112.078 us; speedup vs baseline: 1.2763x; 1.0443x over previous
//
#include <hip/hip_runtime.h>

#define LN_EPS 1e-5f

constexpr int Bn = 4, Nn = 256, Dn = 256, Hn = 256;

// ws layout (floats):
//   aA    @ 0        (1024*256)
//   bB    @ 262144   (1024*256)
//   rC    @ 524288   (1024)   -- atomic accumulators r[b,h], zeroed in gemm
//   Cpart @ 525312   (512)
// Ledger (measured r7-r9): fill ~42 (in-window), gemm ~26, pair ~17,
// finish+add+gaps ~9. This round: gemm latency-hiding, pair de-spill,
// finish+add merged.

// ---------------------------------------------------------------------------
// Kernel 1: aA[m,h] = x[m,:]@Wg[:D,h] + bg[h]  (half=0)
//           bB[m,h] = x[m,:]@Wg[D:,h]          (half=1)
// m-tile 2, grid (512,2) => 1024 blocks = 4 blocks/CU, 32 waves/CU.
// 512 threads = (h4 = t&63, dc = t>>6). W loads batched 8-deep (8 float4
// in flight before each FMA block). Block (0,0) zeroes rC.
// ---------------------------------------------------------------------------
__global__ __launch_bounds__(512) void gemm_ab_kernel(
    const float* __restrict__ x, const float* __restrict__ Wg,
    const float* __restrict__ bg, float* __restrict__ aA,
    float* __restrict__ bB, float* __restrict__ rC)
{
    int mt = blockIdx.x;     // 0..511
    int half = blockIdx.y;   // 0 -> a, 1 -> b
    int m0 = mt * 2;
    int t = threadIdx.x;

    if (mt == 0 && half == 0) {
        for (int k = t; k < 1024; k += 512) rC[k] = 0.0f;
    }

    __shared__ float xs[2][256];
    __shared__ float accP[8][2][256];

    if (t < 128)
        reinterpret_cast<float4*>(&xs[0][0])[t] =
            reinterpret_cast<const float4*>(x + m0 * Dn)[t];
    __syncthreads();

    const int h4 = t & 63;
    const int dc = t >> 6;         // wave-uniform
    const float* Wp = Wg + (half ? Dn * Hn : 0) + h4 * 4;

    float4 acc[2];
    acc[0] = make_float4(0.f, 0.f, 0.f, 0.f);
    acc[1] = make_float4(0.f, 0.f, 0.f, 0.f);

    for (int dd0 = 0; dd0 < 32; dd0 += 8) {
        float4 w[8];
#pragma unroll
        for (int r = 0; r < 8; ++r)
            w[r] = *reinterpret_cast<const float4*>(Wp + (dc * 32 + dd0 + r) * Hn);
#pragma unroll
        for (int r = 0; r < 8; ++r) {
            int d = dc * 32 + dd0 + r;
#pragma unroll
            for (int m = 0; m < 2; ++m) {
                float xv = xs[m][d];
                acc[m].x = fmaf(xv, w[r].x, acc[m].x);
                acc[m].y = fmaf(xv, w[r].y, acc[m].y);
                acc[m].z = fmaf(xv, w[r].z, acc[m].z);
                acc[m].w = fmaf(xv, w[r].w, acc[m].w);
            }
        }
    }
#pragma unroll
    for (int m = 0; m < 2; ++m)
        *reinterpret_cast<float4*>(&accP[dc][m][h4 * 4]) = acc[m];
    __syncthreads();

    const int h = t & 255;
    const int m = t >> 8;          // 0..1
    float v = half ? 0.0f : bg[h];
#pragma unroll
    for (int c = 0; c < 8; ++c) v += accP[c][m][h];
    float* outp = half ? bB : aA;
    outp[(m0 + m) * Hn + h] = v;
}

// ---------------------------------------------------------------------------
// Kernel 2: pair block, BARRIER-FREE single pass, NO v-stash (recompute
// relu in the acc pass; ~100 VGPR, fits the (512,2) 128-cap spill-free --
// the r10 stash pushed live state to ~130 and spilled).
// Block = (b, 2 i-rows), 512 threads = (s = t>>4: j-slot, p = t&15: h-group).
// Per j-tile: load b[j][p*16..+15] (contiguous 64B), stats pass, width-16
// butterfly, inv redundant per lane, acc pass recomputes relu. No LDS, no
// barriers in the loop. Epilogue: xor16/32 shuffle, LDS combine, atomics.
// ---------------------------------------------------------------------------
__global__ __launch_bounds__(512, 2) void pair_kernel(
    const float* __restrict__ aA, const float* __restrict__ bB,
    float* __restrict__ rC, float* __restrict__ Cpart)
{
    const int b  = blockIdx.x >> 7;
    const int i0 = (blockIdx.x & 127) * 2;
    const int t  = threadIdx.x;
    const int s  = t >> 4;    // j-slot 0..31
    const int p  = t & 15;    // h-group 0..15

    __shared__ float fred[8][16][33];
    __shared__ float wred[8];

    const float* aArow0 = aA + (b * Nn + i0) * Hn + p * 16;
    const float* aArow1 = aArow0 + Hn;
    float4 A0[4], A1[4];
#pragma unroll
    for (int r = 0; r < 4; ++r) {
        A0[r] = *reinterpret_cast<const float4*>(aArow0 + r * 4);
        A1[r] = *reinterpret_cast<const float4*>(aArow1 + r * 4);
    }

    const float* bbase = bB + b * Nn * Hn + p * 16;

    float4 acc0[4], acc1[4];
#pragma unroll
    for (int r = 0; r < 4; ++r) {
        acc0[r] = make_float4(0.f, 0.f, 0.f, 0.f);
        acc1[r] = make_float4(0.f, 0.f, 0.f, 0.f);
    }
    float Csum = 0.f;

    for (int jt = 0; jt < 8; ++jt) {
        const int j = jt * 32 + s;
        const float* rp = bbase + j * Hn;
        float4 bv[4];
#pragma unroll
        for (int r = 0; r < 4; ++r)
            bv[r] = *reinterpret_cast<const float4*>(rp + r * 4);

        float s0 = 0.f, q0 = 0.f, s1 = 0.f, q1 = 0.f;
#pragma unroll
        for (int r = 0; r < 4; ++r) {
            float v;
            v = fmaxf(A0[r].x + bv[r].x, 0.f); s0 += v; q0 = fmaf(v, v, q0);
            v = fmaxf(A0[r].y + bv[r].y, 0.f); s0 += v; q0 = fmaf(v, v, q0);
            v = fmaxf(A0[r].z + bv[r].z, 0.f); s0 += v; q0 = fmaf(v, v, q0);
            v = fmaxf(A0[r].w + bv[r].w, 0.f); s0 += v; q0 = fmaf(v, v, q0);
            v = fmaxf(A1[r].x + bv[r].x, 0.f); s1 += v; q1 = fmaf(v, v, q1);
            v = fmaxf(A1[r].y + bv[r].y, 0.f); s1 += v; q1 = fmaf(v, v, q1);
            v = fmaxf(A1[r].z + bv[r].z, 0.f); s1 += v; q1 = fmaf(v, v, q1);
            v = fmaxf(A1[r].w + bv[r].w, 0.f); s1 += v; q1 = fmaf(v, v, q1);
        }
#pragma unroll
        for (int off = 1; off <= 8; off <<= 1) {
            s0 += __shfl_xor(s0, off, 16);
            q0 += __shfl_xor(q0, off, 16);
            s1 += __shfl_xor(s1, off, 16);
            q1 += __shfl_xor(q1, off, 16);
        }
        float m0 = s0 * (1.f / 256.f), m1 = s1 * (1.f / 256.f);
        float inv0 = rsqrtf(q0 * (1.f / 256.f) - m0 * m0 + LN_EPS);
        float inv1 = rsqrtf(q1 * (1.f / 256.f) - m1 * m1 + LN_EPS);
        if (p == 0) Csum -= m0 * inv0 + m1 * inv1;
        // acc pass: recompute relu (saves 32 VGPR of stash)
#pragma unroll
        for (int r = 0; r < 4; ++r) {
            acc0[r].x = fmaf(inv0, fmaxf(A0[r].x + bv[r].x, 0.f), acc0[r].x);
            acc0[r].y = fmaf(inv0, fmaxf(A0[r].y + bv[r].y, 0.f), acc0[r].y);
            acc0[r].z = fmaf(inv0, fmaxf(A0[r].z + bv[r].z, 0.f), acc0[r].z);
            acc0[r].w = fmaf(inv0, fmaxf(A0[r].w + bv[r].w, 0.f), acc0[r].w);
            acc1[r].x = fmaf(inv1, fmaxf(A1[r].x + bv[r].x, 0.f), acc1[r].x);
            acc1[r].y = fmaf(inv1, fmaxf(A1[r].y + bv[r].y, 0.f), acc1[r].y);
            acc1[r].z = fmaf(inv1, fmaxf(A1[r].z + bv[r].z, 0.f), acc1[r].z);
            acc1[r].w = fmaf(inv1, fmaxf(A1[r].w + bv[r].w, 0.f), acc1[r].w);
        }
    }

#pragma unroll
    for (int r = 0; r < 4; ++r) {
        acc0[r].x += __shfl_xor(acc0[r].x, 16, 64);
        acc0[r].y += __shfl_xor(acc0[r].y, 16, 64);
        acc0[r].z += __shfl_xor(acc0[r].z, 16, 64);
        acc0[r].w += __shfl_xor(acc0[r].w, 16, 64);
        acc1[r].x += __shfl_xor(acc1[r].x, 16, 64);
        acc1[r].y += __shfl_xor(acc1[r].y, 16, 64);
        acc1[r].z += __shfl_xor(acc1[r].z, 16, 64);
        acc1[r].w += __shfl_xor(acc1[r].w, 16, 64);
    }
#pragma unroll
    for (int r = 0; r < 4; ++r) {
        acc0[r].x += __shfl_xor(acc0[r].x, 32, 64);
        acc0[r].y += __shfl_xor(acc0[r].y, 32, 64);
        acc0[r].z += __shfl_xor(acc0[r].z, 32, 64);
        acc0[r].w += __shfl_xor(acc0[r].w, 32, 64);
        acc1[r].x += __shfl_xor(acc1[r].x, 32, 64);
        acc1[r].y += __shfl_xor(acc1[r].y, 32, 64);
        acc1[r].z += __shfl_xor(acc1[r].z, 32, 64);
        acc1[r].w += __shfl_xor(acc1[r].w, 32, 64);
    }
    const int w = t >> 6;
    if ((t & 63) < 16) {
#pragma unroll
        for (int r = 0; r < 4; ++r) {
            fred[w][p][r * 4 + 0] = acc0[r].x;
            fred[w][p][r * 4 + 1] = acc0[r].y;
            fred[w][p][r * 4 + 2] = acc0[r].z;
            fred[w][p][r * 4 + 3] = acc0[r].w;
            fred[w][p][16 + r * 4 + 0] = acc1[r].x;
            fred[w][p][16 + r * 4 + 1] = acc1[r].y;
            fred[w][p][16 + r * 4 + 2] = acc1[r].z;
            fred[w][p][16 + r * 4 + 3] = acc1[r].w;
        }
    }
    float cs = Csum;
#pragma unroll
    for (int off = 32; off >= 1; off >>= 1) cs += __shfl_xor(cs, off, 64);
    if ((t & 63) == 0) wred[w] = cs;
    __syncthreads();

    {
        const int i  = t >> 8;
        const int h  = t & 255;
        const int pp = h >> 4, hh = h & 15;
        float v = 0.f;
#pragma unroll
        for (int ww = 0; ww < 8; ++ww) v += fred[ww][pp][i * 16 + hh];
        atomicAdd(&rC[b * Hn + h], v);
    }
    if (t == 0) {
        float cb = 0.f;
#pragma unroll
        for (int ww = 0; ww < 8; ++ww) cb += wred[ww];
        Cpart[blockIdx.x] = cb;
    }
}

// ---------------------------------------------------------------------------
// Kernel 3: finish + add merged. Grid 64 = (b, 16-row slice), 512 threads.
// Each block redundantly computes rel[b,:] (Cpart reduce, GEMV, relu, LN),
// then writes its 16 n-rows of out = rel + x. Saves a launch + rel trip.
// ---------------------------------------------------------------------------
__global__ __launch_bounds__(512) void finish_add_kernel(
    const float* __restrict__ rC, const float* __restrict__ Cpart,
    const float* __restrict__ gg, const float* __restrict__ gb,
    const float* __restrict__ Wf, const float* __restrict__ bfv,
    const float* __restrict__ fg, const float* __restrict__ fb,
    const float* __restrict__ x, float* __restrict__ out)
{
    const int b = blockIdx.x >> 4;
    const int slice = blockIdx.x & 15;
    const int t = threadIdx.x;
    __shared__ float rs[256];
    __shared__ float relS[256];
    __shared__ float ysum[8][260];
    __shared__ float cred[2];
    __shared__ float pS[4], pQ[4];

    float cv = (t < 128) ? Cpart[b * 128 + t] : 0.f;
#pragma unroll
    for (int off = 32; off >= 1; off >>= 1) cv += __shfl_xor(cv, off, 64);
    if (t == 0 || t == 64) cred[t >> 6] = cv;
    __syncthreads();

    if (t < 256) {
        float Cb = cred[0] + cred[1];
        rs[t] = gg[t] * (rC[b * Hn + t] + Cb) + 65536.0f * gb[t];
    }
    __syncthreads();

    const int h4 = t & 63;
    const int kc = t >> 6;
    float4 acc = make_float4(0.f, 0.f, 0.f, 0.f);
    const float* Wp = Wf + h4 * 4;
#pragma unroll 8
    for (int kk = 0; kk < 32; ++kk) {
        int k = kc * 32 + kk;
        float4 w = *reinterpret_cast<const float4*>(Wp + k * Hn);
        float rv = rs[k];
        acc.x = fmaf(rv, w.x, acc.x);
        acc.y = fmaf(rv, w.y, acc.y);
        acc.z = fmaf(rv, w.z, acc.z);
        acc.w = fmaf(rv, w.w, acc.w);
    }
    *reinterpret_cast<float4*>(&ysum[kc][h4 * 4]) = acc;
    __syncthreads();

    float v = 0.f;
    if (t < 256) {
        v = bfv[t];
#pragma unroll
        for (int c = 0; c < 8; ++c) v += ysum[c][t];
        v = fmaxf(v, 0.f);
    }
    float sv = (t < 256) ? v : 0.f;
    float qv = (t < 256) ? v * v : 0.f;
#pragma unroll
    for (int off = 32; off >= 1; off >>= 1) {
        sv += __shfl_xor(sv, off, 64);
        qv += __shfl_xor(qv, off, 64);
    }
    if (t < 256 && (t & 63) == 0) { pS[t >> 6] = sv; pQ[t >> 6] = qv; }
    __syncthreads();

    if (t < 256) {
        float S = pS[0] + pS[1] + pS[2] + pS[3];
        float Q = pQ[0] + pQ[1] + pQ[2] + pQ[3];
        float m = S * (1.f / 256.f);
        float inv = rsqrtf(Q * (1.f / 256.f) - m * m + LN_EPS);
        relS[t] = (v - m) * inv * fg[t] + fb[t];
    }
    __syncthreads();

    // write 16 n-rows: 4096 floats = 1024 float4; 2 per thread
    const int base4 = (b * Nn + slice * 16) * (Hn / 4);
#pragma unroll
    for (int kq = 0; kq < 2; ++kq) {
        int k = kq * 512 + t;          // 0..1023
        int col4 = k & 63;
        float4 xv = reinterpret_cast<const float4*>(x)[base4 + k];
        float4 r4 = *reinterpret_cast<const float4*>(&relS[col4 * 4]);
        float4 o;
        o.x = xv.x + r4.x;
        o.y = xv.y + r4.y;
        o.z = xv.z + r4.z;
        o.w = xv.w + r4.w;
        reinterpret_cast<float4*>(out)[base4 + k] = o;
    }
}

// ---------------------------------------------------------------------------
extern "C" void kernel_launch(void* const* d_in, const int* in_sizes, int n_in,
                              void* d_out, int out_size, void* d_ws, size_t ws_size,
                              hipStream_t stream)
{
    const float* x   = (const float*)d_in[0];
    const float* Wg  = (const float*)d_in[1];
    const float* bg  = (const float*)d_in[2];
    const float* gg  = (const float*)d_in[3];
    const float* gb  = (const float*)d_in[4];
    const float* Wf  = (const float*)d_in[5];
    const float* bfv = (const float*)d_in[6];
    const float* fg  = (const float*)d_in[7];
    const float* fb  = (const float*)d_in[8];
    float* out = (float*)d_out;

    float* ws    = (float*)d_ws;
    float* aA    = ws;                 // 1024*256
    float* bB    = ws + 262144;        // 1024*256
    float* rC    = ws + 524288;        // 1024
    float* Cpart = ws + 525312;        // 512

    gemm_ab_kernel<<<dim3(512, 2), 512, 0, stream>>>(x, Wg, bg, aA, bB, rC);
    pair_kernel<<<512, 512, 0, stream>>>(aA, bB, rC, Cpart);
    finish_add_kernel<<<64, 512, 0, stream>>>(rC, Cpart, gg, gb, Wf, bfv,
                                              fg, fb, x, out);
}